// Round 5
// baseline (426.486 us; speedup 1.0000x reference)
//
#include <hip/hip_runtime.h>

#define SLOPE 0.2f

typedef unsigned int uint;
typedef unsigned short ushort;
typedef __attribute__((ext_vector_type(8))) short short8;
typedef __attribute__((ext_vector_type(4))) float f32x4;
typedef __attribute__((ext_vector_type(2))) uint uint2v;
typedef __attribute__((ext_vector_type(4))) uint uint4v;

#define BINW 2048
#define BINSHIFT 11

__device__ inline ushort f2bf(float f) {
    uint u = __float_as_uint(f);
    uint r = (u + 0x7FFFu + ((u >> 16) & 1u)) >> 16;
    return (ushort)r;
}
__device__ inline uint pack2bf(float lo, float hi) {
    return (uint)f2bf(lo) | ((uint)f2bf(hi) << 16);
}
__device__ inline float bfl(uint u) { return __uint_as_float(u << 16); }
__device__ inline float bfh(uint u) { return __uint_as_float(u & 0xFFFF0000u); }

// ---------------- W -> WT bf16 transposed [n][k], 3 relations ----------------
__global__ void wt3(const float* __restrict__ W0, const float* __restrict__ W1,
                    const float* __restrict__ W2, ushort* __restrict__ WT) {
    int r = blockIdx.x;
    const float* W = (r == 0) ? W0 : (r == 1) ? W1 : W2;
    ushort* wt = WT + r * 16384;
    for (int i = threadIdx.x; i < 16384; i += 256) {
        int k = i >> 7, n = i & 127;
        wt[n * 128 + k] = f2bf(W[i]);
    }
}

// ------- MFMA GEMM + fused scores: Wh_r = H@W_r (bf16); sd/ss from fp32 acc -------
__global__ __launch_bounds__(256) void gemm3(const float* __restrict__ H,
                                             const ushort* __restrict__ WT,
                                             const float* __restrict__ a0,
                                             const float* __restrict__ a1,
                                             const float* __restrict__ a2,
                                             ushort* __restrict__ Wh0,
                                             ushort* __restrict__ Wh1,
                                             ushort* __restrict__ Wh2,
                                             float* __restrict__ sd,
                                             float* __restrict__ ss, int N) {
    __shared__ ushort lds[16384];  // 128 x 128 bf16, XOR-swizzled
    __shared__ float sds[128], sss[128];
    const int brow = blockIdx.x * 128;
    const int t = threadIdx.x;

    for (int c = t; c < 2048; c += 256) {
        int r = c >> 4;
        int kb = (c & 15) << 4;
        int gr = brow + r;
        uint4 u = make_uint4(0, 0, 0, 0);
        if (gr < N) {
            const float* hp = H + (size_t)gr * 128 + (kb >> 1);
            float4 v0 = *reinterpret_cast<const float4*>(hp);
            float4 v1 = *reinterpret_cast<const float4*>(hp + 4);
            u.x = pack2bf(v0.x, v0.y);
            u.y = pack2bf(v0.z, v0.w);
            u.z = pack2bf(v1.x, v1.y);
            u.w = pack2bf(v1.z, v1.w);
        }
        int dst = (r << 8) + (kb ^ ((r & 7) << 4));
        *reinterpret_cast<uint4*>((char*)lds + dst) = u;
    }
    if (t < 128) { sds[t] = 0.f; sss[t] = 0.f; }
    __syncthreads();

    const int wave = t >> 6, lane = t & 63;
    const int l16 = lane & 15, lhi = lane >> 4;

    for (int rel = 0; rel < 3; ++rel) {
        ushort* Wh = (rel == 0) ? Wh0 : (rel == 1) ? Wh1 : Wh2;
        const float* aP = (rel == 0) ? a0 : (rel == 1) ? a1 : a2;
        const ushort* wt = WT + rel * 16384;

        short8 bf[2][4];
#pragma unroll
        for (int nt = 0; nt < 2; ++nt) {
            int n = wave * 32 + nt * 16 + l16;
#pragma unroll
            for (int ks = 0; ks < 4; ++ks)
                bf[nt][ks] = *reinterpret_cast<const short8*>(wt + n * 128 + ks * 32 + lhi * 8);
        }

        f32x4 acc[8][2];
#pragma unroll
        for (int mt = 0; mt < 8; ++mt) { acc[mt][0] = (f32x4)(0.f); acc[mt][1] = (f32x4)(0.f); }

#pragma unroll
        for (int ks = 0; ks < 4; ++ks) {
#pragma unroll
            for (int mt = 0; mt < 8; ++mt) {
                int r = mt * 16 + l16;
                int kb = (ks * 32 + lhi * 8) * 2;
                int addr = (r << 8) + (kb ^ ((r & 7) << 4));
                short8 af = *reinterpret_cast<const short8*>((char*)lds + addr);
                acc[mt][0] = __builtin_amdgcn_mfma_f32_16x16x32_bf16(af, bf[0][ks], acc[mt][0], 0, 0, 0);
                acc[mt][1] = __builtin_amdgcn_mfma_f32_16x16x32_bf16(af, bf[1][ks], acc[mt][1], 0, 0, 0);
            }
        }

        // fused scores: per-row partial dot over this thread's 2 cols, 16-lane reduce
        const int c0 = wave * 32 + l16;
        const float aL0 = aP[c0], aL1 = aP[c0 + 16];
        const float aR0 = aP[128 + c0], aR1 = aP[128 + c0 + 16];
#pragma unroll
        for (int mt = 0; mt < 8; ++mt)
#pragma unroll
            for (int reg = 0; reg < 4; ++reg) {
                float pd = acc[mt][0][reg] * aL0 + acc[mt][1][reg] * aL1;
                float ps = acc[mt][0][reg] * aR0 + acc[mt][1][reg] * aR1;
#pragma unroll
                for (int off = 1; off < 16; off <<= 1) {
                    pd += __shfl_xor(pd, off);
                    ps += __shfl_xor(ps, off);
                }
                if (l16 == 0) {
                    int rloc = mt * 16 + lhi * 4 + reg;
                    atomicAdd(&sds[rloc], pd);
                    atomicAdd(&sss[rloc], ps);
                }
            }

        // Wh store
#pragma unroll
        for (int mt = 0; mt < 8; ++mt)
#pragma unroll
            for (int nt = 0; nt < 2; ++nt)
#pragma unroll
                for (int reg = 0; reg < 4; ++reg) {
                    int gr = brow + mt * 16 + lhi * 4 + reg;
                    if (gr < N)
                        Wh[(size_t)gr * 128 + wave * 32 + nt * 16 + l16] = f2bf(acc[mt][nt][reg]);
                }

        __syncthreads();
        if (t < 128) {
            int gr = brow + t;
            if (gr < N) { sd[rel * N + gr] = sds[t]; ss[rel * N + gr] = sss[t]; }
            sds[t] = 0.f; sss[t] = 0.f;
        }
        __syncthreads();
    }
}

// ---------------- coarse-bin histogram ----------------
__global__ __launch_bounds__(256) void binhist(const int* __restrict__ r0,
                                               const int* __restrict__ r1,
                                               const int* __restrict__ r2,
                                               int* __restrict__ bincnt, int E, int N, int nbins) {
    __shared__ int h[256];
    int t = threadIdx.x;
    h[t] = 0;
    __syncthreads();
    int base = blockIdx.x * 4096;
#pragma unroll
    for (int k = 0; k < 16; ++k) {
        int i = base + k * 256 + t;
        if (i < 3 * E) {
            int r = (i >= 2 * E) ? 2 : (i >= E) ? 1 : 0;
            int li = i - r * E;
            const int* rp = (r == 0) ? r0 : (r == 1) ? r1 : r2;
            int idx = r * N + __builtin_nontemporal_load(rp + li);
            atomicAdd(&h[idx >> BINSHIFT], 1);
        }
    }
    __syncthreads();
    if (t < nbins && h[t]) atomicAdd(&bincnt[t], h[t]);
}

// ---------------- bin base scan ----------------
__global__ __launch_bounds__(256) void binscan(const int* __restrict__ bincnt,
                                               int* __restrict__ binbase,
                                               int* __restrict__ gbincur, int nbins, int total) {
    __shared__ int sA[256], sB[256];
    int t = threadIdx.x;
    int v = (t < nbins) ? bincnt[t] : 0;
    sA[t] = v;
    __syncthreads();
    int* pa = sA; int* pb = sB;
    for (int off = 1; off < 256; off <<= 1) {
        int x = pa[t] + ((t >= off) ? pa[t - off] : 0);
        pb[t] = x;
        __syncthreads();
        int* tmp = pa; pa = pb; pb = tmp;
    }
    if (t < nbins) {
        int excl = pa[t] - v;
        binbase[t] = excl;
        gbincur[t] = excl;
    }
    if (t == 0) binbase[nbins] = total;
}

// ---------------- phase 1: bin-group records, coalesced NT flush ----------------
__global__ __launch_bounds__(256) void binscatter(const int* __restrict__ r0, const int* __restrict__ r1,
                                                  const int* __restrict__ r2, const int* __restrict__ c0,
                                                  const int* __restrict__ c1, const int* __restrict__ c2,
                                                  const float* __restrict__ sd, const float* __restrict__ ss,
                                                  int* __restrict__ gbincur, uint2v* __restrict__ binned,
                                                  int E, int N, int nbins) {
    __shared__ uint2 staged[4096];
    __shared__ int hist[256], sB[256], curi[256], gbase[256];
    const int t = threadIdx.x;
    hist[t] = 0;
    __syncthreads();

    uint2 rec[16];
    short bn[16];
    const int base = blockIdx.x * 4096;
#pragma unroll
    for (int k = 0; k < 16; ++k) {
        int i = base + k * 256 + t;
        bn[k] = -1;
        if (i < 3 * E) {
            int r = (i >= 2 * E) ? 2 : (i >= E) ? 1 : 0;
            int li = i - r * E;
            const int* rp = (r == 0) ? r0 : (r == 1) ? r1 : r2;
            const int* cp = (r == 0) ? c0 : (r == 1) ? c1 : c2;
            int rr = __builtin_nontemporal_load(rp + li);
            int cc = __builtin_nontemporal_load(cp + li);
            int idx = r * N + rr;
            int b = idx >> BINSHIFT;
            uint lo = (uint)(idx & (BINW - 1));
            float x = sd[idx] + ss[r * N + cc];
            x = (x > 0.f) ? x : SLOPE * x;
            float w = __expf(x);
            rec[k] = make_uint2((uint)cc | (lo << 17), __float_as_uint(w));
            bn[k] = (short)b;
            atomicAdd(&hist[b], 1);
        }
    }
    __syncthreads();

    int v = hist[t];
    int* pa = hist; int* pb = sB;
    for (int off = 1; off < 256; off <<= 1) {
        int x = pa[t] + ((t >= off) ? pa[t - off] : 0);
        pb[t] = x;
        __syncthreads();
        int* tmp = pa; pa = pb; pb = tmp;
    }
    sB[t] = pa[t] - v;
    curi[t] = pa[t] - v;
    if (t < nbins && v > 0) gbase[t] = atomicAdd(&gbincur[t], v);
    __syncthreads();

#pragma unroll
    for (int k = 0; k < 16; ++k)
        if (bn[k] >= 0) {
            int p = atomicAdd(&curi[bn[k]], 1);
            staged[p] = rec[k];
        }
    __syncthreads();

    const int wave = t >> 6, lane = t & 63;
    for (int b = wave; b < nbins; b += 4) {
        int s = sB[b];
        int len = hist[b] - s;
        if (len <= 0) continue;
        int g = gbase[b];
        for (int j = lane; j < len; j += 64) {
            uint2 rr = staged[s + j];
            uint2v val; val.x = rr.x; val.y = rr.y;
            __builtin_nontemporal_store(val, binned + g + j);
        }
    }
}

// ---------------- phase 2: per-bin counting sort -> wc + offs ----------------
__global__ __launch_bounds__(256) void binsort(const uint2* __restrict__ binned,
                                               const int* __restrict__ binbase,
                                               uint2v* __restrict__ wc, int* __restrict__ offs, int L) {
    __shared__ int s1[BINW], s2[BINW];
    const int b = blockIdx.x, t = threadIdx.x;
    const int start = binbase[b], end = binbase[b + 1];
    const int ibase = b << BINSHIFT;
    const int width = min(BINW, L - ibase);

    for (int i = t; i < BINW; i += 256) s1[i] = 0;
    __syncthreads();
    for (int j = start + t; j < end; j += 256) {
        uint lo = (binned[j].x >> 17) & (BINW - 1);
        atomicAdd(&s1[lo], 1);
    }
    __syncthreads();

    int* pa = s1; int* pb = s2;
    for (int off = 1; off < BINW; off <<= 1) {
        for (int i = t; i < BINW; i += 256)
            pb[i] = pa[i] + ((i >= off) ? pa[i - off] : 0);
        __syncthreads();
        int* tmp = pa; pa = pb; pb = tmp;
    }
    for (int i = t; i < width; i += 256) offs[ibase + i] = start + pa[i];
    for (int i = t; i < BINW; i += 256) pb[i] = i ? pa[i - 1] : 0;
    __syncthreads();

    for (int j = start + t; j < end; j += 256) {
        uint2 r = binned[j];
        uint lo = (r.x >> 17) & (BINW - 1);
        int p = atomicAdd(&pb[lo], 1);
        uint2v val; val.x = r.y; val.y = r.x & 0x1FFFFu;
        __builtin_nontemporal_store(val, wc + start + p);
    }
}

// ------- aggregation: quarter-wave per node, cooperative wc load + shfl broadcast -------
__global__ __launch_bounds__(256) void aggregate3(const uint* __restrict__ wh0,
                                                  const uint* __restrict__ wh1,
                                                  const uint* __restrict__ wh2,
                                                  const uint2v* __restrict__ wc,
                                                  const int* __restrict__ offs,
                                                  const float* __restrict__ bias,
                                                  float* __restrict__ out, int N) {
    int node = blockIdx.x * 16 + (threadIdx.x >> 4);
    int lane = threadIdx.x & 63;
    int ql = lane & 15;
    int gb = lane & 48;   // 16-lane group base within wave
    if (node >= N) return;

    float t0 = 0.f, t1 = 0.f, t2 = 0.f, t3 = 0.f, t4 = 0.f, t5 = 0.f, t6 = 0.f, t7 = 0.f;

#pragma unroll
    for (int r = 0; r < 3; ++r) {
        const uint* wh = (r == 0) ? wh0 : (r == 1) ? wh1 : wh2;
        int idx = r * N + node;
        int end = offs[idx];
        int beg = (idx == 0) ? 0 : offs[idx - 1];
        int cnt = end - beg;
        if (cnt <= 0) continue;
        float wsum = 0.f;
        float a0 = 0.f, a1 = 0.f, a2 = 0.f, a3 = 0.f, a4 = 0.f, a5 = 0.f, a6 = 0.f, a7 = 0.f;

        for (int base = 0; base < cnt; base += 16) {
            int m = cnt - base; if (m > 16) m = 16;
            uint ex = 0, ey = 0;
            if (ql < m) {
                uint2v e = __builtin_nontemporal_load(wc + beg + base + ql);
                ex = e.x; ey = e.y;
            }
            for (int k = 0; k < m; ++k) {
                float w = __uint_as_float((uint)__shfl((int)ex, gb + k));
                uint cc = (uint)__shfl((int)ey, gb + k);
                uint4v v = *(reinterpret_cast<const uint4v*>(wh + ((size_t)cc << 6)) + ql);
                wsum += w;
                a0 = fmaf(w, bfl(v.x), a0);
                a1 = fmaf(w, bfh(v.x), a1);
                a2 = fmaf(w, bfl(v.y), a2);
                a3 = fmaf(w, bfh(v.y), a3);
                a4 = fmaf(w, bfl(v.z), a4);
                a5 = fmaf(w, bfh(v.z), a5);
                a6 = fmaf(w, bfl(v.w), a6);
                a7 = fmaf(w, bfh(v.w), a7);
            }
        }
        float inv = 1.f / fmaxf(wsum, 1e-12f);
        t0 = fmaf(a0, inv, t0); t1 = fmaf(a1, inv, t1);
        t2 = fmaf(a2, inv, t2); t3 = fmaf(a3, inv, t3);
        t4 = fmaf(a4, inv, t4); t5 = fmaf(a5, inv, t5);
        t6 = fmaf(a6, inv, t6); t7 = fmaf(a7, inv, t7);
    }

    float4 b0 = *reinterpret_cast<const float4*>(bias + ql * 8);
    float4 b1 = *reinterpret_cast<const float4*>(bias + ql * 8 + 4);
    float* o = out + (size_t)node * 128 + ql * 8;
    f32x4 o0 = {t0 + b0.x, t1 + b0.y, t2 + b0.z, t3 + b0.w};
    f32x4 o1 = {t4 + b1.x, t5 + b1.y, t6 + b1.z, t7 + b1.w};
    __builtin_nontemporal_store(o0, reinterpret_cast<f32x4*>(o));
    __builtin_nontemporal_store(o1, reinterpret_cast<f32x4*>(o + 4));
}

// ---------------- launch ----------------
extern "C" void kernel_launch(void* const* d_in, const int* in_sizes, int n_in,
                              void* d_out, int out_size, void* d_ws, size_t ws_size,
                              hipStream_t stream) {
    const float* H = (const float*)d_in[0];
    const int* row[3] = {(const int*)d_in[1], (const int*)d_in[5], (const int*)d_in[9]};
    const int* col[3] = {(const int*)d_in[2], (const int*)d_in[6], (const int*)d_in[10]};
    const float* W[3] = {(const float*)d_in[3], (const float*)d_in[7], (const float*)d_in[11]};
    const float* a[3] = {(const float*)d_in[4], (const float*)d_in[8], (const float*)d_in[12]};
    const float* bias = (const float*)d_in[13];

    const int N = in_sizes[0] / 128;
    const int E = in_sizes[1];
    float* out = (float*)d_out;

    const int L = 3 * N;
    const int nbins = (L + BINW - 1) >> BINSHIFT;

    char* ws = (char*)d_ws;
    size_t off = 0;
    auto alloc = [&](size_t bytes) -> void* {
        void* p = ws + off;
        off += (bytes + 255) & ~(size_t)255;
        return p;
    };

    ushort* WT = (ushort*)alloc(3 * 16384 * 2);
    ushort* Wh[3];
    for (int r = 0; r < 3; ++r) Wh[r] = (ushort*)alloc((size_t)N * 128 * 2);
    float* sd = (float*)alloc((size_t)L * 4);
    float* ss = (float*)alloc((size_t)L * 4);
    int* offs = (int*)alloc((size_t)L * 4);
    int* bincnt = (int*)alloc((size_t)(nbins + 2) * 4);
    int* binbase = (int*)alloc((size_t)(nbins + 2) * 4);
    int* gbincur = (int*)alloc((size_t)(nbins + 2) * 4);
    uint2v* wc = (uint2v*)alloc((size_t)3 * E * 8);
    uint2v* binned = (uint2v*)d_out;  // scratch inside output buffer (dead until aggregate)

    const int nbG = (N + 127) / 128;
    const int nbQ = (N + 15) / 16;
    const int nbB = (3 * E + 4095) / 4096;

    wt3<<<3, 256, 0, stream>>>(W[0], W[1], W[2], WT);
    gemm3<<<nbG, 256, 0, stream>>>(H, WT, a[0], a[1], a[2], Wh[0], Wh[1], Wh[2], sd, ss, N);

    hipMemsetAsync(bincnt, 0, (size_t)(nbins + 2) * 4, stream);
    binhist<<<nbB, 256, 0, stream>>>(row[0], row[1], row[2], bincnt, E, N, nbins);
    binscan<<<1, 256, 0, stream>>>(bincnt, binbase, gbincur, nbins, 3 * E);
    binscatter<<<nbB, 256, 0, stream>>>(row[0], row[1], row[2], col[0], col[1], col[2],
                                        sd, ss, gbincur, binned, E, N, nbins);
    binsort<<<nbins, 256, 0, stream>>>((const uint2*)binned, binbase, wc, offs, L);

    aggregate3<<<nbQ, 256, 0, stream>>>((const uint*)Wh[0], (const uint*)Wh[1], (const uint*)Wh[2],
                                        wc, offs, bias, out, N);
}

// Round 6
// 354.040 us; speedup vs baseline: 1.2046x; 1.2046x over previous
//
#include <hip/hip_runtime.h>

#define SLOPE 0.2f

typedef unsigned int uint;
typedef unsigned short ushort;
typedef __attribute__((ext_vector_type(8))) short short8;
typedef __attribute__((ext_vector_type(4))) float f32x4;

#define BINW 2048
#define BINSHIFT 11

__device__ inline ushort f2bf(float f) {
    uint u = __float_as_uint(f);
    uint r = (u + 0x7FFFu + ((u >> 16) & 1u)) >> 16;
    return (ushort)r;
}
__device__ inline uint pack2bf(float lo, float hi) {
    return (uint)f2bf(lo) | ((uint)f2bf(hi) << 16);
}
__device__ inline float bfl(uint u) { return __uint_as_float(u << 16); }
__device__ inline float bfh(uint u) { return __uint_as_float(u & 0xFFFF0000u); }

// ---------------- W -> WT bf16 transposed [n][k], 3 relations ----------------
__global__ void wt3(const float* __restrict__ W0, const float* __restrict__ W1,
                    const float* __restrict__ W2, ushort* __restrict__ WT) {
    int r = blockIdx.x;
    const float* W = (r == 0) ? W0 : (r == 1) ? W1 : W2;
    ushort* wt = WT + r * 16384;
    for (int i = threadIdx.x; i < 16384; i += 256) {
        int k = i >> 7, n = i & 127;
        wt[n * 128 + k] = f2bf(W[i]);
    }
}

// ------- MFMA GEMM + fused scores: Wh_r = H@W_r (bf16); sd/ss from fp32 acc -------
__global__ __launch_bounds__(256) void gemm3(const float* __restrict__ H,
                                             const ushort* __restrict__ WT,
                                             const float* __restrict__ a0,
                                             const float* __restrict__ a1,
                                             const float* __restrict__ a2,
                                             ushort* __restrict__ Wh0,
                                             ushort* __restrict__ Wh1,
                                             ushort* __restrict__ Wh2,
                                             float* __restrict__ sd,
                                             float* __restrict__ ss, int N) {
    __shared__ ushort lds[16384];  // 128 x 128 bf16, XOR-swizzled
    __shared__ float sds[128], sss[128];
    const int brow = blockIdx.x * 128;
    const int t = threadIdx.x;

    for (int c = t; c < 2048; c += 256) {
        int r = c >> 4;
        int kb = (c & 15) << 4;
        int gr = brow + r;
        uint4 u = make_uint4(0, 0, 0, 0);
        if (gr < N) {
            const float* hp = H + (size_t)gr * 128 + (kb >> 1);
            float4 v0 = *reinterpret_cast<const float4*>(hp);
            float4 v1 = *reinterpret_cast<const float4*>(hp + 4);
            u.x = pack2bf(v0.x, v0.y);
            u.y = pack2bf(v0.z, v0.w);
            u.z = pack2bf(v1.x, v1.y);
            u.w = pack2bf(v1.z, v1.w);
        }
        int dst = (r << 8) + (kb ^ ((r & 7) << 4));
        *reinterpret_cast<uint4*>((char*)lds + dst) = u;
    }
    if (t < 128) { sds[t] = 0.f; sss[t] = 0.f; }
    __syncthreads();

    const int wave = t >> 6, lane = t & 63;
    const int l16 = lane & 15, lhi = lane >> 4;

    for (int rel = 0; rel < 3; ++rel) {
        ushort* Wh = (rel == 0) ? Wh0 : (rel == 1) ? Wh1 : Wh2;
        const float* aP = (rel == 0) ? a0 : (rel == 1) ? a1 : a2;
        const ushort* wt = WT + rel * 16384;

        short8 bf[2][4];
#pragma unroll
        for (int nt = 0; nt < 2; ++nt) {
            int n = wave * 32 + nt * 16 + l16;
#pragma unroll
            for (int ks = 0; ks < 4; ++ks)
                bf[nt][ks] = *reinterpret_cast<const short8*>(wt + n * 128 + ks * 32 + lhi * 8);
        }

        f32x4 acc[8][2];
#pragma unroll
        for (int mt = 0; mt < 8; ++mt) { acc[mt][0] = (f32x4)(0.f); acc[mt][1] = (f32x4)(0.f); }

#pragma unroll
        for (int ks = 0; ks < 4; ++ks) {
#pragma unroll
            for (int mt = 0; mt < 8; ++mt) {
                int r = mt * 16 + l16;
                int kb = (ks * 32 + lhi * 8) * 2;
                int addr = (r << 8) + (kb ^ ((r & 7) << 4));
                short8 af = *reinterpret_cast<const short8*>((char*)lds + addr);
                acc[mt][0] = __builtin_amdgcn_mfma_f32_16x16x32_bf16(af, bf[0][ks], acc[mt][0], 0, 0, 0);
                acc[mt][1] = __builtin_amdgcn_mfma_f32_16x16x32_bf16(af, bf[1][ks], acc[mt][1], 0, 0, 0);
            }
        }

        // fused scores: per-row partial dot over this thread's 2 cols, 16-lane reduce
        const int c0 = wave * 32 + l16;
        const float aL0 = aP[c0], aL1 = aP[c0 + 16];
        const float aR0 = aP[128 + c0], aR1 = aP[128 + c0 + 16];
#pragma unroll
        for (int mt = 0; mt < 8; ++mt)
#pragma unroll
            for (int reg = 0; reg < 4; ++reg) {
                float pd = acc[mt][0][reg] * aL0 + acc[mt][1][reg] * aL1;
                float ps = acc[mt][0][reg] * aR0 + acc[mt][1][reg] * aR1;
#pragma unroll
                for (int off = 1; off < 16; off <<= 1) {
                    pd += __shfl_xor(pd, off);
                    ps += __shfl_xor(ps, off);
                }
                if (l16 == 0) {
                    int rloc = mt * 16 + lhi * 4 + reg;
                    atomicAdd(&sds[rloc], pd);
                    atomicAdd(&sss[rloc], ps);
                }
            }

        // Wh store
#pragma unroll
        for (int mt = 0; mt < 8; ++mt)
#pragma unroll
            for (int nt = 0; nt < 2; ++nt)
#pragma unroll
                for (int reg = 0; reg < 4; ++reg) {
                    int gr = brow + mt * 16 + lhi * 4 + reg;
                    if (gr < N)
                        Wh[(size_t)gr * 128 + wave * 32 + nt * 16 + l16] = f2bf(acc[mt][nt][reg]);
                }

        __syncthreads();
        if (t < 128) {
            int gr = brow + t;
            if (gr < N) { sd[rel * N + gr] = sds[t]; ss[rel * N + gr] = sss[t]; }
            sds[t] = 0.f; sss[t] = 0.f;
        }
        __syncthreads();
    }
}

// ---------------- coarse-bin histogram ----------------
__global__ __launch_bounds__(256) void binhist(const int* __restrict__ r0,
                                               const int* __restrict__ r1,
                                               const int* __restrict__ r2,
                                               int* __restrict__ bincnt, int E, int N, int nbins) {
    __shared__ int h[256];
    int t = threadIdx.x;
    h[t] = 0;
    __syncthreads();
    int base = blockIdx.x * 4096;
#pragma unroll
    for (int k = 0; k < 16; ++k) {
        int i = base + k * 256 + t;
        if (i < 3 * E) {
            int r = (i >= 2 * E) ? 2 : (i >= E) ? 1 : 0;
            int li = i - r * E;
            const int* rp = (r == 0) ? r0 : (r == 1) ? r1 : r2;
            int idx = r * N + __builtin_nontemporal_load(rp + li);
            atomicAdd(&h[idx >> BINSHIFT], 1);
        }
    }
    __syncthreads();
    if (t < nbins && h[t]) atomicAdd(&bincnt[t], h[t]);
}

// ---------------- bin base scan ----------------
__global__ __launch_bounds__(256) void binscan(const int* __restrict__ bincnt,
                                               int* __restrict__ binbase,
                                               int* __restrict__ gbincur, int nbins, int total) {
    __shared__ int sA[256], sB[256];
    int t = threadIdx.x;
    int v = (t < nbins) ? bincnt[t] : 0;
    sA[t] = v;
    __syncthreads();
    int* pa = sA; int* pb = sB;
    for (int off = 1; off < 256; off <<= 1) {
        int x = pa[t] + ((t >= off) ? pa[t - off] : 0);
        pb[t] = x;
        __syncthreads();
        int* tmp = pa; pa = pb; pb = tmp;
    }
    if (t < nbins) {
        int excl = pa[t] - v;
        binbase[t] = excl;
        gbincur[t] = excl;
    }
    if (t == 0) binbase[nbins] = total;
}

// ---------------- phase 1: bin-group records, coalesced flush (stays in L2) ----------------
__global__ __launch_bounds__(256) void binscatter(const int* __restrict__ r0, const int* __restrict__ r1,
                                                  const int* __restrict__ r2, const int* __restrict__ c0,
                                                  const int* __restrict__ c1, const int* __restrict__ c2,
                                                  const float* __restrict__ sd, const float* __restrict__ ss,
                                                  int* __restrict__ gbincur, uint2* __restrict__ binned,
                                                  int E, int N, int nbins) {
    __shared__ uint2 staged[4096];
    __shared__ int hist[256], sB[256], curi[256], gbase[256];
    const int t = threadIdx.x;
    hist[t] = 0;
    __syncthreads();

    uint2 rec[16];
    short bn[16];
    const int base = blockIdx.x * 4096;
#pragma unroll
    for (int k = 0; k < 16; ++k) {
        int i = base + k * 256 + t;
        bn[k] = -1;
        if (i < 3 * E) {
            int r = (i >= 2 * E) ? 2 : (i >= E) ? 1 : 0;
            int li = i - r * E;
            const int* rp = (r == 0) ? r0 : (r == 1) ? r1 : r2;
            const int* cp = (r == 0) ? c0 : (r == 1) ? c1 : c2;
            int rr = __builtin_nontemporal_load(rp + li);
            int cc = __builtin_nontemporal_load(cp + li);
            int idx = r * N + rr;
            int b = idx >> BINSHIFT;
            uint lo = (uint)(idx & (BINW - 1));
            float x = sd[idx] + ss[r * N + cc];
            x = (x > 0.f) ? x : SLOPE * x;
            float w = __expf(x);
            rec[k] = make_uint2((uint)cc | (lo << 17), __float_as_uint(w));
            bn[k] = (short)b;
            atomicAdd(&hist[b], 1);
        }
    }
    __syncthreads();

    int v = hist[t];
    int* pa = hist; int* pb = sB;
    for (int off = 1; off < 256; off <<= 1) {
        int x = pa[t] + ((t >= off) ? pa[t - off] : 0);
        pb[t] = x;
        __syncthreads();
        int* tmp = pa; pa = pb; pb = tmp;
    }
    sB[t] = pa[t] - v;
    curi[t] = pa[t] - v;
    if (t < nbins && v > 0) gbase[t] = atomicAdd(&gbincur[t], v);
    __syncthreads();

#pragma unroll
    for (int k = 0; k < 16; ++k)
        if (bn[k] >= 0) {
            int p = atomicAdd(&curi[bn[k]], 1);
            staged[p] = rec[k];
        }
    __syncthreads();

    const int wave = t >> 6, lane = t & 63;
    for (int b = wave; b < nbins; b += 4) {
        int s = sB[b];
        int len = hist[b] - s;
        if (len <= 0) continue;
        int g = gbase[b];
        for (int j = lane; j < len; j += 64) binned[g + j] = staged[s + j];
    }
}

// ---------------- phase 2: per-bin counting sort (hierarchical scan) ----------------
__global__ __launch_bounds__(256) void binsort(const uint2* __restrict__ binned,
                                               const int* __restrict__ binbase,
                                               uint2* __restrict__ wc, int* __restrict__ offs, int L) {
    __shared__ int s1[BINW];
    __shared__ int wsum[4];
    const int b = blockIdx.x, t = threadIdx.x;
    const int start = binbase[b], end = binbase[b + 1];
    const int ibase = b << BINSHIFT;
    const int width = min(BINW, L - ibase);

    for (int i = t; i < BINW; i += 256) s1[i] = 0;
    __syncthreads();
    for (int j = start + t; j < end; j += 256)
        atomicAdd(&s1[(binned[j].x >> 17) & (BINW - 1)], 1);
    __syncthreads();

    // hierarchical inclusive scan: 8/thread registers -> wave shfl scan -> 4 wave sums
    const int cb = t * 8;
    int v[8];
    int run = 0;
#pragma unroll
    for (int k = 0; k < 8; ++k) { run += s1[cb + k]; v[k] = run; }
    const int lane = t & 63, wv = t >> 6;
    int x = run;
#pragma unroll
    for (int off = 1; off < 64; off <<= 1) {
        int y = __shfl_up(x, off);
        if (lane >= off) x += y;
    }
    if (lane == 63) wsum[wv] = x;
    __syncthreads();
    int pre = x - run;                       // exclusive prefix within wave
#pragma unroll
    for (int w = 0; w < 3; ++w) if (wv > w) pre += wsum[w];

#pragma unroll
    for (int k = 0; k < 8; ++k) {
        int i = cb + k;
        if (i < width) offs[ibase + i] = start + pre + v[k];   // inclusive -> bucket end
    }
#pragma unroll
    for (int k = 0; k < 8; ++k)
        s1[cb + k] = start + pre + (k ? v[k - 1] : 0);         // exclusive cursor (global)
    __syncthreads();

    for (int j = start + t; j < end; j += 256) {
        uint2 r = binned[j];
        uint lo = (r.x >> 17) & (BINW - 1);
        int p = atomicAdd(&s1[lo], 1);
        wc[p] = make_uint2(r.y, r.x & 0x1FFFFu);   // {w bits, col}
    }
}

// ---------------- aggregation: quarter-wave per node (round-4 proven body) ----------------
__global__ __launch_bounds__(256) void aggregate3(const uint* __restrict__ wh0,
                                                  const uint* __restrict__ wh1,
                                                  const uint* __restrict__ wh2,
                                                  const uint2* __restrict__ wc,
                                                  const int* __restrict__ offs,
                                                  const float* __restrict__ bias,
                                                  float* __restrict__ out, int N) {
    int node = blockIdx.x * 16 + (threadIdx.x >> 4);
    int ql = threadIdx.x & 15;
    if (node >= N) return;

    float t0 = 0.f, t1 = 0.f, t2 = 0.f, t3 = 0.f, t4 = 0.f, t5 = 0.f, t6 = 0.f, t7 = 0.f;

#pragma unroll
    for (int r = 0; r < 3; ++r) {
        const uint* wh = (r == 0) ? wh0 : (r == 1) ? wh1 : wh2;
        int idx = r * N + node;
        int end = offs[idx];
        int beg = (idx == 0) ? 0 : offs[idx - 1];
        if (beg >= end) continue;
        float wsum = 0.f;
        float a0 = 0.f, a1 = 0.f, a2 = 0.f, a3 = 0.f, a4 = 0.f, a5 = 0.f, a6 = 0.f, a7 = 0.f;
        for (int j = beg; j < end; ++j) {
            uint2 e = wc[j];
            float w = __uint_as_float(e.x);
            int c = (int)e.y;
            uint4 v = reinterpret_cast<const uint4*>(wh + ((size_t)c << 6))[ql];
            wsum += w;
            a0 = fmaf(w, bfl(v.x), a0);
            a1 = fmaf(w, bfh(v.x), a1);
            a2 = fmaf(w, bfl(v.y), a2);
            a3 = fmaf(w, bfh(v.y), a3);
            a4 = fmaf(w, bfl(v.z), a4);
            a5 = fmaf(w, bfh(v.z), a5);
            a6 = fmaf(w, bfl(v.w), a6);
            a7 = fmaf(w, bfh(v.w), a7);
        }
        float inv = 1.f / fmaxf(wsum, 1e-12f);
        t0 = fmaf(a0, inv, t0); t1 = fmaf(a1, inv, t1);
        t2 = fmaf(a2, inv, t2); t3 = fmaf(a3, inv, t3);
        t4 = fmaf(a4, inv, t4); t5 = fmaf(a5, inv, t5);
        t6 = fmaf(a6, inv, t6); t7 = fmaf(a7, inv, t7);
    }

    float4 b0 = *reinterpret_cast<const float4*>(bias + ql * 8);
    float4 b1 = *reinterpret_cast<const float4*>(bias + ql * 8 + 4);
    float* o = out + (size_t)node * 128 + ql * 8;
    f32x4 o0 = {t0 + b0.x, t1 + b0.y, t2 + b0.z, t3 + b0.w};
    f32x4 o1 = {t4 + b1.x, t5 + b1.y, t6 + b1.z, t7 + b1.w};
    __builtin_nontemporal_store(o0, reinterpret_cast<f32x4*>(o));
    __builtin_nontemporal_store(o1, reinterpret_cast<f32x4*>(o + 4));
}

// ---------------- launch ----------------
extern "C" void kernel_launch(void* const* d_in, const int* in_sizes, int n_in,
                              void* d_out, int out_size, void* d_ws, size_t ws_size,
                              hipStream_t stream) {
    const float* H = (const float*)d_in[0];
    const int* row[3] = {(const int*)d_in[1], (const int*)d_in[5], (const int*)d_in[9]};
    const int* col[3] = {(const int*)d_in[2], (const int*)d_in[6], (const int*)d_in[10]};
    const float* W[3] = {(const float*)d_in[3], (const float*)d_in[7], (const float*)d_in[11]};
    const float* a[3] = {(const float*)d_in[4], (const float*)d_in[8], (const float*)d_in[12]};
    const float* bias = (const float*)d_in[13];

    const int N = in_sizes[0] / 128;
    const int E = in_sizes[1];
    float* out = (float*)d_out;

    const int L = 3 * N;
    const int nbins = (L + BINW - 1) >> BINSHIFT;

    char* ws = (char*)d_ws;
    size_t off = 0;
    auto alloc = [&](size_t bytes) -> void* {
        void* p = ws + off;
        off += (bytes + 255) & ~(size_t)255;
        return p;
    };

    ushort* WT = (ushort*)alloc(3 * 16384 * 2);
    ushort* Wh[3];
    for (int r = 0; r < 3; ++r) Wh[r] = (ushort*)alloc((size_t)N * 128 * 2);
    float* sd = (float*)alloc((size_t)L * 4);
    float* ss = (float*)alloc((size_t)L * 4);
    int* offs = (int*)alloc((size_t)L * 4);
    int* bincnt = (int*)alloc((size_t)(nbins + 2) * 4);
    int* binbase = (int*)alloc((size_t)(nbins + 2) * 4);
    int* gbincur = (int*)alloc((size_t)(nbins + 2) * 4);
    uint2* wc = (uint2*)alloc((size_t)3 * E * 8);
    uint2* binned = (uint2*)d_out;  // scratch inside output buffer (dead until aggregate)

    const int nbG = (N + 127) / 128;
    const int nbQ = (N + 15) / 16;
    const int nbB = (3 * E + 4095) / 4096;

    wt3<<<3, 256, 0, stream>>>(W[0], W[1], W[2], WT);
    gemm3<<<nbG, 256, 0, stream>>>(H, WT, a[0], a[1], a[2], Wh[0], Wh[1], Wh[2], sd, ss, N);

    hipMemsetAsync(bincnt, 0, (size_t)(nbins + 2) * 4, stream);
    binhist<<<nbB, 256, 0, stream>>>(row[0], row[1], row[2], bincnt, E, N, nbins);
    binscan<<<1, 256, 0, stream>>>(bincnt, binbase, gbincur, nbins, 3 * E);
    binscatter<<<nbB, 256, 0, stream>>>(row[0], row[1], row[2], col[0], col[1], col[2],
                                        sd, ss, gbincur, binned, E, N, nbins);
    binsort<<<nbins, 256, 0, stream>>>(binned, binbase, wc, offs, L);

    aggregate3<<<nbQ, 256, 0, stream>>>((const uint*)Wh[0], (const uint*)Wh[1], (const uint*)Wh[2],
                                        wc, offs, bias, out, N);
}

// Round 7
// 319.016 us; speedup vs baseline: 1.3369x; 1.1098x over previous
//
#include <hip/hip_runtime.h>

#define SLOPE 0.2f

typedef unsigned int uint;
typedef unsigned short ushort;
typedef __attribute__((ext_vector_type(8))) short short8;
typedef __attribute__((ext_vector_type(4))) float f32x4;

#define BINW 2048
#define BINSHIFT 11

__device__ inline ushort f2bf(float f) {
    uint u = __float_as_uint(f);
    uint r = (u + 0x7FFFu + ((u >> 16) & 1u)) >> 16;
    return (ushort)r;
}
__device__ inline uint pack2bf(float lo, float hi) {
    return (uint)f2bf(lo) | ((uint)f2bf(hi) << 16);
}
__device__ inline float bfl(uint u) { return __uint_as_float(u << 16); }
__device__ inline float bfh(uint u) { return __uint_as_float(u & 0xFFFF0000u); }

// ---------------- W -> WT bf16 transposed [n][k], 3 relations ----------------
__global__ void wt3(const float* __restrict__ W0, const float* __restrict__ W1,
                    const float* __restrict__ W2, ushort* __restrict__ WT) {
    int r = blockIdx.x;
    const float* W = (r == 0) ? W0 : (r == 1) ? W1 : W2;
    ushort* wt = WT + r * 16384;
    for (int i = threadIdx.x; i < 16384; i += 256) {
        int k = i >> 7, n = i & 127;
        wt[n * 128 + k] = f2bf(W[i]);
    }
}

// ---------------- MFMA GEMM: Wh_r(bf16) = H @ W_r; H tile staged ONCE for 3 rels ----
__global__ __launch_bounds__(256) void gemm3(const float* __restrict__ H,
                                             const ushort* __restrict__ WT,
                                             ushort* __restrict__ Wh0,
                                             ushort* __restrict__ Wh1,
                                             ushort* __restrict__ Wh2, int N) {
    __shared__ ushort lds[16384];  // 128 rows x 128 bf16, XOR-swizzled
    const int brow = blockIdx.x * 128;
    const int t = threadIdx.x;

    for (int c = t; c < 2048; c += 256) {
        int r = c >> 4;
        int kb = (c & 15) << 4;
        int gr = brow + r;
        uint4 u = make_uint4(0, 0, 0, 0);
        if (gr < N) {
            const float* hp = H + (size_t)gr * 128 + (kb >> 1);
            float4 v0 = *reinterpret_cast<const float4*>(hp);
            float4 v1 = *reinterpret_cast<const float4*>(hp + 4);
            u.x = pack2bf(v0.x, v0.y);
            u.y = pack2bf(v0.z, v0.w);
            u.z = pack2bf(v1.x, v1.y);
            u.w = pack2bf(v1.z, v1.w);
        }
        int dst = (r << 8) + (kb ^ ((r & 7) << 4));
        *reinterpret_cast<uint4*>((char*)lds + dst) = u;
    }
    __syncthreads();

    const int wave = t >> 6, lane = t & 63;
    const int l16 = lane & 15, lhi = lane >> 4;

    for (int rel = 0; rel < 3; ++rel) {
        ushort* Wh = (rel == 0) ? Wh0 : (rel == 1) ? Wh1 : Wh2;
        const ushort* wt = WT + rel * 16384;

        short8 bf[2][4];
#pragma unroll
        for (int nt = 0; nt < 2; ++nt) {
            int n = wave * 32 + nt * 16 + l16;
#pragma unroll
            for (int ks = 0; ks < 4; ++ks)
                bf[nt][ks] = *reinterpret_cast<const short8*>(wt + n * 128 + ks * 32 + lhi * 8);
        }

        f32x4 acc[8][2];
#pragma unroll
        for (int mt = 0; mt < 8; ++mt) { acc[mt][0] = (f32x4)(0.f); acc[mt][1] = (f32x4)(0.f); }

#pragma unroll
        for (int ks = 0; ks < 4; ++ks) {
#pragma unroll
            for (int mt = 0; mt < 8; ++mt) {
                int r = mt * 16 + l16;
                int kb = (ks * 32 + lhi * 8) * 2;
                int addr = (r << 8) + (kb ^ ((r & 7) << 4));
                short8 af = *reinterpret_cast<const short8*>((char*)lds + addr);
                acc[mt][0] = __builtin_amdgcn_mfma_f32_16x16x32_bf16(af, bf[0][ks], acc[mt][0], 0, 0, 0);
                acc[mt][1] = __builtin_amdgcn_mfma_f32_16x16x32_bf16(af, bf[1][ks], acc[mt][1], 0, 0, 0);
            }
        }

#pragma unroll
        for (int mt = 0; mt < 8; ++mt)
#pragma unroll
            for (int nt = 0; nt < 2; ++nt)
#pragma unroll
                for (int reg = 0; reg < 4; ++reg) {
                    int gr = brow + mt * 16 + lhi * 4 + reg;
                    if (gr < N)
                        Wh[(size_t)gr * 128 + wave * 32 + nt * 16 + l16] = f2bf(acc[mt][nt][reg]);
                }
    }
}

// ---------------- scores: quarter-wave per node, 3 relations ----------------
__global__ __launch_bounds__(256) void scores_k(const uint* __restrict__ wh0,
                                                const uint* __restrict__ wh1,
                                                const uint* __restrict__ wh2,
                                                const float* __restrict__ a0,
                                                const float* __restrict__ a1,
                                                const float* __restrict__ a2,
                                                float* __restrict__ sd,
                                                float* __restrict__ ss, int N) {
    int node = blockIdx.x * 16 + (threadIdx.x >> 4);
    int ql = threadIdx.x & 15;
    if (node >= N) return;
#pragma unroll
    for (int r = 0; r < 3; ++r) {
        const uint* wh = (r == 0) ? wh0 : (r == 1) ? wh1 : wh2;
        const float* a = (r == 0) ? a0 : (r == 1) ? a1 : a2;
        const uint4 v = reinterpret_cast<const uint4*>(wh + ((size_t)node << 6))[ql];
        float f0 = bfl(v.x), f1 = bfh(v.x), f2 = bfl(v.y), f3 = bfh(v.y);
        float f4 = bfl(v.z), f5 = bfh(v.z), f6 = bfl(v.w), f7 = bfh(v.w);
        float4 aL0 = *reinterpret_cast<const float4*>(a + ql * 8);
        float4 aL1 = *reinterpret_cast<const float4*>(a + ql * 8 + 4);
        float4 aR0 = *reinterpret_cast<const float4*>(a + 128 + ql * 8);
        float4 aR1 = *reinterpret_cast<const float4*>(a + 128 + ql * 8 + 4);
        float pd = f0 * aL0.x + f1 * aL0.y + f2 * aL0.z + f3 * aL0.w +
                   f4 * aL1.x + f5 * aL1.y + f6 * aL1.z + f7 * aL1.w;
        float ps = f0 * aR0.x + f1 * aR0.y + f2 * aR0.z + f3 * aR0.w +
                   f4 * aR1.x + f5 * aR1.y + f6 * aR1.z + f7 * aR1.w;
#pragma unroll
        for (int off = 1; off < 16; off <<= 1) {
            pd += __shfl_xor(pd, off);
            ps += __shfl_xor(ps, off);
        }
        if (ql == 0) { sd[r * N + node] = pd; ss[r * N + node] = ps; }
    }
}

// ---------------- coarse-bin histogram ----------------
__global__ __launch_bounds__(256) void binhist(const int* __restrict__ r0,
                                               const int* __restrict__ r1,
                                               const int* __restrict__ r2,
                                               int* __restrict__ bincnt, int E, int N, int nbins) {
    __shared__ int h[256];
    int t = threadIdx.x;
    h[t] = 0;
    __syncthreads();
    int base = blockIdx.x * 4096;
#pragma unroll
    for (int k = 0; k < 16; ++k) {
        int i = base + k * 256 + t;
        if (i < 3 * E) {
            int r = (i >= 2 * E) ? 2 : (i >= E) ? 1 : 0;
            int li = i - r * E;
            const int* rp = (r == 0) ? r0 : (r == 1) ? r1 : r2;
            int idx = r * N + __builtin_nontemporal_load(rp + li);
            atomicAdd(&h[idx >> BINSHIFT], 1);
        }
    }
    __syncthreads();
    if (t < nbins && h[t]) atomicAdd(&bincnt[t], h[t]);
}

// ---------------- bin base scan ----------------
__global__ __launch_bounds__(256) void binscan(const int* __restrict__ bincnt,
                                               int* __restrict__ binbase,
                                               int* __restrict__ gbincur, int nbins, int total) {
    __shared__ int sA[256], sB[256];
    int t = threadIdx.x;
    int v = (t < nbins) ? bincnt[t] : 0;
    sA[t] = v;
    __syncthreads();
    int* pa = sA; int* pb = sB;
    for (int off = 1; off < 256; off <<= 1) {
        int x = pa[t] + ((t >= off) ? pa[t - off] : 0);
        pb[t] = x;
        __syncthreads();
        int* tmp = pa; pa = pb; pb = tmp;
    }
    if (t < nbins) {
        int excl = pa[t] - v;
        binbase[t] = excl;
        gbincur[t] = excl;
    }
    if (t == 0) binbase[nbins] = total;
}

// ---------------- phase 1: bin-group records, coalesced flush (stays in L2) ----------------
__global__ __launch_bounds__(256) void binscatter(const int* __restrict__ r0, const int* __restrict__ r1,
                                                  const int* __restrict__ r2, const int* __restrict__ c0,
                                                  const int* __restrict__ c1, const int* __restrict__ c2,
                                                  const float* __restrict__ sd, const float* __restrict__ ss,
                                                  int* __restrict__ gbincur, uint2* __restrict__ binned,
                                                  int E, int N, int nbins) {
    __shared__ uint2 staged[4096];
    __shared__ int hist[256], sB[256], curi[256], gbase[256];
    const int t = threadIdx.x;
    hist[t] = 0;
    __syncthreads();

    uint2 rec[16];
    short bn[16];
    const int base = blockIdx.x * 4096;
#pragma unroll
    for (int k = 0; k < 16; ++k) {
        int i = base + k * 256 + t;
        bn[k] = -1;
        if (i < 3 * E) {
            int r = (i >= 2 * E) ? 2 : (i >= E) ? 1 : 0;
            int li = i - r * E;
            const int* rp = (r == 0) ? r0 : (r == 1) ? r1 : r2;
            const int* cp = (r == 0) ? c0 : (r == 1) ? c1 : c2;
            int rr = __builtin_nontemporal_load(rp + li);
            int cc = __builtin_nontemporal_load(cp + li);
            int idx = r * N + rr;
            int b = idx >> BINSHIFT;
            uint lo = (uint)(idx & (BINW - 1));
            float x = sd[idx] + ss[r * N + cc];
            x = (x > 0.f) ? x : SLOPE * x;
            float w = __expf(x);
            rec[k] = make_uint2((uint)cc | (lo << 17), __float_as_uint(w));
            bn[k] = (short)b;
            atomicAdd(&hist[b], 1);
        }
    }
    __syncthreads();

    int v = hist[t];
    int* pa = hist; int* pb = sB;
    for (int off = 1; off < 256; off <<= 1) {
        int x = pa[t] + ((t >= off) ? pa[t - off] : 0);
        pb[t] = x;
        __syncthreads();
        int* tmp = pa; pa = pb; pb = tmp;
    }
    sB[t] = pa[t] - v;
    curi[t] = pa[t] - v;
    if (t < nbins && v > 0) gbase[t] = atomicAdd(&gbincur[t], v);
    __syncthreads();

#pragma unroll
    for (int k = 0; k < 16; ++k)
        if (bn[k] >= 0) {
            int p = atomicAdd(&curi[bn[k]], 1);
            staged[p] = rec[k];
        }
    __syncthreads();

    const int wave = t >> 6, lane = t & 63;
    for (int b = wave; b < nbins; b += 4) {
        int s = sB[b];
        int len = hist[b] - s;
        if (len <= 0) continue;
        int g = gbase[b];
        for (int j = lane; j < len; j += 64) binned[g + j] = staged[s + j];
    }
}

// ---------------- phase 2: per-bin counting sort (hierarchical scan) ----------------
__global__ __launch_bounds__(256) void binsort(const uint2* __restrict__ binned,
                                               const int* __restrict__ binbase,
                                               uint2* __restrict__ wc, int* __restrict__ offs, int L) {
    __shared__ int s1[BINW];
    __shared__ int wsum[4];
    const int b = blockIdx.x, t = threadIdx.x;
    const int start = binbase[b], end = binbase[b + 1];
    const int ibase = b << BINSHIFT;
    const int width = min(BINW, L - ibase);

    for (int i = t; i < BINW; i += 256) s1[i] = 0;
    __syncthreads();
    for (int j = start + t; j < end; j += 256)
        atomicAdd(&s1[(binned[j].x >> 17) & (BINW - 1)], 1);
    __syncthreads();

    const int cb = t * 8;
    int v[8];
    int run = 0;
#pragma unroll
    for (int k = 0; k < 8; ++k) { run += s1[cb + k]; v[k] = run; }
    const int lane = t & 63, wv = t >> 6;
    int x = run;
#pragma unroll
    for (int off = 1; off < 64; off <<= 1) {
        int y = __shfl_up(x, off);
        if (lane >= off) x += y;
    }
    if (lane == 63) wsum[wv] = x;
    __syncthreads();
    int pre = x - run;
#pragma unroll
    for (int w = 0; w < 3; ++w) if (wv > w) pre += wsum[w];

#pragma unroll
    for (int k = 0; k < 8; ++k) {
        int i = cb + k;
        if (i < width) offs[ibase + i] = start + pre + v[k];
    }
#pragma unroll
    for (int k = 0; k < 8; ++k)
        s1[cb + k] = start + pre + (k ? v[k - 1] : 0);
    __syncthreads();

    for (int j = start + t; j < end; j += 256) {
        uint2 r = binned[j];
        uint lo = (r.x >> 17) & (BINW - 1);
        int p = atomicAdd(&s1[lo], 1);
        wc[p] = make_uint2(r.y, r.x & 0x1FFFFu);
    }
}

// ------- aggregation: quarter-wave per node, 4-deep unrolled gather pipeline -------
__global__ __launch_bounds__(256) void aggregate3(const uint* __restrict__ wh0,
                                                  const uint* __restrict__ wh1,
                                                  const uint* __restrict__ wh2,
                                                  const uint2* __restrict__ wc,
                                                  const int* __restrict__ offs,
                                                  const float* __restrict__ bias,
                                                  float* __restrict__ out, int N) {
    int node = blockIdx.x * 16 + (threadIdx.x >> 4);
    int ql = threadIdx.x & 15;
    if (node >= N) return;

    float t0 = 0.f, t1 = 0.f, t2 = 0.f, t3 = 0.f, t4 = 0.f, t5 = 0.f, t6 = 0.f, t7 = 0.f;

#pragma unroll
    for (int r = 0; r < 3; ++r) {
        const uint* wh = (r == 0) ? wh0 : (r == 1) ? wh1 : wh2;
        int idx = r * N + node;
        int end = offs[idx];
        int beg = (idx == 0) ? 0 : offs[idx - 1];
        if (beg >= end) continue;

        float wsA = 0.f, wsB = 0.f;
        float a0 = 0.f, a1 = 0.f, a2 = 0.f, a3 = 0.f, a4 = 0.f, a5 = 0.f, a6 = 0.f, a7 = 0.f;
        float g0 = 0.f, g1 = 0.f, g2 = 0.f, g3 = 0.f, g4 = 0.f, g5 = 0.f, g6 = 0.f, g7 = 0.f;

        int j = beg;
        for (; j + 4 <= end; j += 4) {
            uint2 e0 = wc[j], e1 = wc[j + 1], e2 = wc[j + 2], e3 = wc[j + 3];
            uint4 v0 = reinterpret_cast<const uint4*>(wh + ((size_t)e0.y << 6))[ql];
            uint4 v1 = reinterpret_cast<const uint4*>(wh + ((size_t)e1.y << 6))[ql];
            uint4 v2 = reinterpret_cast<const uint4*>(wh + ((size_t)e2.y << 6))[ql];
            uint4 v3 = reinterpret_cast<const uint4*>(wh + ((size_t)e3.y << 6))[ql];
            float w0 = __uint_as_float(e0.x), w1 = __uint_as_float(e1.x);
            float w2 = __uint_as_float(e2.x), w3 = __uint_as_float(e3.x);
            wsA += w0 + w2;
            wsB += w1 + w3;
            a0 = fmaf(w0, bfl(v0.x), a0); a1 = fmaf(w0, bfh(v0.x), a1);
            a2 = fmaf(w0, bfl(v0.y), a2); a3 = fmaf(w0, bfh(v0.y), a3);
            a4 = fmaf(w0, bfl(v0.z), a4); a5 = fmaf(w0, bfh(v0.z), a5);
            a6 = fmaf(w0, bfl(v0.w), a6); a7 = fmaf(w0, bfh(v0.w), a7);
            g0 = fmaf(w1, bfl(v1.x), g0); g1 = fmaf(w1, bfh(v1.x), g1);
            g2 = fmaf(w1, bfl(v1.y), g2); g3 = fmaf(w1, bfh(v1.y), g3);
            g4 = fmaf(w1, bfl(v1.z), g4); g5 = fmaf(w1, bfh(v1.z), g5);
            g6 = fmaf(w1, bfl(v1.w), g6); g7 = fmaf(w1, bfh(v1.w), g7);
            a0 = fmaf(w2, bfl(v2.x), a0); a1 = fmaf(w2, bfh(v2.x), a1);
            a2 = fmaf(w2, bfl(v2.y), a2); a3 = fmaf(w2, bfh(v2.y), a3);
            a4 = fmaf(w2, bfl(v2.z), a4); a5 = fmaf(w2, bfh(v2.z), a5);
            a6 = fmaf(w2, bfl(v2.w), a6); a7 = fmaf(w2, bfh(v2.w), a7);
            g0 = fmaf(w3, bfl(v3.x), g0); g1 = fmaf(w3, bfh(v3.x), g1);
            g2 = fmaf(w3, bfl(v3.y), g2); g3 = fmaf(w3, bfh(v3.y), g3);
            g4 = fmaf(w3, bfl(v3.z), g4); g5 = fmaf(w3, bfh(v3.z), g5);
            g6 = fmaf(w3, bfl(v3.w), g6); g7 = fmaf(w3, bfh(v3.w), g7);
        }
        for (; j < end; ++j) {
            uint2 e = wc[j];
            float w = __uint_as_float(e.x);
            uint4 v = reinterpret_cast<const uint4*>(wh + ((size_t)e.y << 6))[ql];
            wsA += w;
            a0 = fmaf(w, bfl(v.x), a0); a1 = fmaf(w, bfh(v.x), a1);
            a2 = fmaf(w, bfl(v.y), a2); a3 = fmaf(w, bfh(v.y), a3);
            a4 = fmaf(w, bfl(v.z), a4); a5 = fmaf(w, bfh(v.z), a5);
            a6 = fmaf(w, bfl(v.w), a6); a7 = fmaf(w, bfh(v.w), a7);
        }
        float inv = 1.f / fmaxf(wsA + wsB, 1e-12f);
        t0 = fmaf(a0 + g0, inv, t0); t1 = fmaf(a1 + g1, inv, t1);
        t2 = fmaf(a2 + g2, inv, t2); t3 = fmaf(a3 + g3, inv, t3);
        t4 = fmaf(a4 + g4, inv, t4); t5 = fmaf(a5 + g5, inv, t5);
        t6 = fmaf(a6 + g6, inv, t6); t7 = fmaf(a7 + g7, inv, t7);
    }

    float4 b0 = *reinterpret_cast<const float4*>(bias + ql * 8);
    float4 b1 = *reinterpret_cast<const float4*>(bias + ql * 8 + 4);
    float* o = out + (size_t)node * 128 + ql * 8;
    f32x4 o0 = {t0 + b0.x, t1 + b0.y, t2 + b0.z, t3 + b0.w};
    f32x4 o1 = {t4 + b1.x, t5 + b1.y, t6 + b1.z, t7 + b1.w};
    __builtin_nontemporal_store(o0, reinterpret_cast<f32x4*>(o));
    __builtin_nontemporal_store(o1, reinterpret_cast<f32x4*>(o + 4));
}

// ---------------- launch ----------------
extern "C" void kernel_launch(void* const* d_in, const int* in_sizes, int n_in,
                              void* d_out, int out_size, void* d_ws, size_t ws_size,
                              hipStream_t stream) {
    const float* H = (const float*)d_in[0];
    const int* row[3] = {(const int*)d_in[1], (const int*)d_in[5], (const int*)d_in[9]};
    const int* col[3] = {(const int*)d_in[2], (const int*)d_in[6], (const int*)d_in[10]};
    const float* W[3] = {(const float*)d_in[3], (const float*)d_in[7], (const float*)d_in[11]};
    const float* a[3] = {(const float*)d_in[4], (const float*)d_in[8], (const float*)d_in[12]};
    const float* bias = (const float*)d_in[13];

    const int N = in_sizes[0] / 128;
    const int E = in_sizes[1];
    float* out = (float*)d_out;

    const int L = 3 * N;
    const int nbins = (L + BINW - 1) >> BINSHIFT;

    char* ws = (char*)d_ws;
    size_t off = 0;
    auto alloc = [&](size_t bytes) -> void* {
        void* p = ws + off;
        off += (bytes + 255) & ~(size_t)255;
        return p;
    };

    ushort* WT = (ushort*)alloc(3 * 16384 * 2);
    ushort* Wh[3];
    for (int r = 0; r < 3; ++r) Wh[r] = (ushort*)alloc((size_t)N * 128 * 2);
    float* sd = (float*)alloc((size_t)L * 4);
    float* ss = (float*)alloc((size_t)L * 4);
    int* offs = (int*)alloc((size_t)L * 4);
    int* bincnt = (int*)alloc((size_t)(nbins + 2) * 4);
    int* binbase = (int*)alloc((size_t)(nbins + 2) * 4);
    int* gbincur = (int*)alloc((size_t)(nbins + 2) * 4);
    uint2* wc = (uint2*)alloc((size_t)3 * E * 8);
    uint2* binned = (uint2*)d_out;  // scratch inside output buffer (dead until aggregate)

    const int nbG = (N + 127) / 128;
    const int nbQ = (N + 15) / 16;
    const int nbB = (3 * E + 4095) / 4096;

    wt3<<<3, 256, 0, stream>>>(W[0], W[1], W[2], WT);
    gemm3<<<nbG, 256, 0, stream>>>(H, WT, Wh[0], Wh[1], Wh[2], N);
    scores_k<<<nbQ, 256, 0, stream>>>((const uint*)Wh[0], (const uint*)Wh[1], (const uint*)Wh[2],
                                      a[0], a[1], a[2], sd, ss, N);

    hipMemsetAsync(bincnt, 0, (size_t)(nbins + 2) * 4, stream);
    binhist<<<nbB, 256, 0, stream>>>(row[0], row[1], row[2], bincnt, E, N, nbins);
    binscan<<<1, 256, 0, stream>>>(bincnt, binbase, gbincur, nbins, 3 * E);
    binscatter<<<nbB, 256, 0, stream>>>(row[0], row[1], row[2], col[0], col[1], col[2],
                                        sd, ss, gbincur, binned, E, N, nbins);
    binsort<<<nbins, 256, 0, stream>>>(binned, binbase, wc, offs, L);

    aggregate3<<<nbQ, 256, 0, stream>>>((const uint*)Wh[0], (const uint*)Wh[1], (const uint*)Wh[2],
                                        wc, offs, bias, out, N);
}